// Round 2
// baseline (1417.136 us; speedup 1.0000x reference)
//
#include <hip/hip_runtime.h>
#include <hip/hip_bf16.h>
#include <math.h>

// Problem constants
#define BB 2
#define SS 1024
#define DD 768
#define HH 12
#define DHH 64
#define MM 64
#define DFF 3072
#define BS (BB*SS)          // 2048 rows
#define EPS_LN 1e-5f
#define EPS_PHI 1e-6f

// ---------------------------------------------------------------------------
// LayerNorm: one block per row, 256 threads, D=768 -> 3 elems/thread
// ---------------------------------------------------------------------------
__global__ __launch_bounds__(256) void ln_kernel(const float* __restrict__ x,
                                                 const float* __restrict__ g,
                                                 const float* __restrict__ bta,
                                                 float* __restrict__ out) {
    int row = blockIdx.x;
    int t = threadIdx.x;
    const float* xr = x + (size_t)row * DD;
    float v0 = xr[t], v1 = xr[t + 256], v2 = xr[t + 512];
    float s = v0 + v1 + v2;
    float s2 = v0 * v0 + v1 * v1 + v2 * v2;
    // wave butterfly
    #pragma unroll
    for (int off = 32; off > 0; off >>= 1) {
        s  += __shfl_xor(s,  off, 64);
        s2 += __shfl_xor(s2, off, 64);
    }
    __shared__ float ls[4], ls2[4];
    if ((t & 63) == 0) { ls[t >> 6] = s; ls2[t >> 6] = s2; }
    __syncthreads();
    s  = ls[0] + ls[1] + ls[2] + ls[3];
    s2 = ls2[0] + ls2[1] + ls2[2] + ls2[3];
    float mu  = s * (1.0f / DD);
    float var = s2 * (1.0f / DD) - mu * mu;
    float r = rsqrtf(var + EPS_LN);
    float* orow = out + (size_t)row * DD;
    orow[t]       = (v0 - mu) * r * g[t]       + bta[t];
    orow[t + 256] = (v1 - mu) * r * g[t + 256] + bta[t + 256];
    orow[t + 512] = (v2 - mu) * r * g[t + 512] + bta[t + 512];
}

// ---------------------------------------------------------------------------
// GEMM: C[Mr x N] = A[Mr x K] @ B[K x N] + bias (+ gelu) (+ residual)
// 64x64 block tile, 16x16 threads, 4x4 micro-tile, BK=16.
// All dims assumed multiples of 64/16 (true here).
// ---------------------------------------------------------------------------
__device__ inline float gelu_tanh(float x) {
    float x3 = x * x * x;
    float u = 0.7978845608028654f * (x + 0.044715f * x3);
    return 0.5f * x * (1.0f + tanhf(u));
}

template <int ACT, bool HAS_RES>
__global__ __launch_bounds__(256) void gemm_kernel(const float* __restrict__ A,
                                                   const float* __restrict__ B,
                                                   const float* __restrict__ bias,
                                                   const float* __restrict__ res,
                                                   float* __restrict__ C,
                                                   int Mr, int N, int K) {
    __shared__ float As[16][65];
    __shared__ float Bs[16][68];
    int tid = threadIdx.x;
    int tx = tid & 15, ty = tid >> 4;
    int rowBase = blockIdx.y * 64, colBase = blockIdx.x * 64;
    float acc[4][4] = {};

    int ka = tid & 15, i0 = (tid >> 4) * 4;   // A-load: col kk+ka, rows i0..i0+3
    int kb = tid >> 4, cb = (tid & 15) * 4;   // B-load: row kk+kb, cols cb..cb+3

    for (int kk = 0; kk < K; kk += 16) {
        #pragma unroll
        for (int j = 0; j < 4; j++)
            As[ka][i0 + j] = A[(size_t)(rowBase + i0 + j) * K + kk + ka];
        float4 bv = *(const float4*)&B[(size_t)(kk + kb) * N + colBase + cb];
        Bs[kb][cb] = bv.x; Bs[kb][cb + 1] = bv.y; Bs[kb][cb + 2] = bv.z; Bs[kb][cb + 3] = bv.w;
        __syncthreads();
        #pragma unroll
        for (int k = 0; k < 16; k++) {
            float a0 = As[k][ty * 4], a1 = As[k][ty * 4 + 1];
            float a2 = As[k][ty * 4 + 2], a3 = As[k][ty * 4 + 3];
            float b0 = Bs[k][tx * 4], b1 = Bs[k][tx * 4 + 1];
            float b2 = Bs[k][tx * 4 + 2], b3 = Bs[k][tx * 4 + 3];
            acc[0][0] += a0 * b0; acc[0][1] += a0 * b1; acc[0][2] += a0 * b2; acc[0][3] += a0 * b3;
            acc[1][0] += a1 * b0; acc[1][1] += a1 * b1; acc[1][2] += a1 * b2; acc[1][3] += a1 * b3;
            acc[2][0] += a2 * b0; acc[2][1] += a2 * b1; acc[2][2] += a2 * b2; acc[2][3] += a2 * b3;
            acc[3][0] += a3 * b0; acc[3][1] += a3 * b1; acc[3][2] += a3 * b2; acc[3][3] += a3 * b3;
        }
        __syncthreads();
    }
    #pragma unroll
    for (int i = 0; i < 4; i++) {
        int row = rowBase + ty * 4 + i;
        #pragma unroll
        for (int j = 0; j < 4; j++) {
            int col = colBase + tx * 4 + j;
            float v = acc[i][j] + bias[col];
            if (ACT == 1) v = gelu_tanh(v);
            if (HAS_RES) v += res[(size_t)row * N + col];
            C[(size_t)row * N + col] = v;
        }
    }
}

// ---------------------------------------------------------------------------
// FAVOR+ features: phi = exp(proj - 0.5*||x||^2) / sqrt(M) + eps
// grid (S, H, 2*B): z -> b = z>>1, isK = z&1.  64 threads, lane = m.
// qkv layout: [B,S,3*D]; q at offset 0, k at 768; head h -> +h*64.
// phi layout: [(b*H+h), s, m]
// ---------------------------------------------------------------------------
__global__ __launch_bounds__(64) void phi_kernel(const float* __restrict__ qkv,
                                                 const float* __restrict__ wfeat,
                                                 float* __restrict__ phiq,
                                                 float* __restrict__ phik) {
    int s = blockIdx.x, h = blockIdx.y, z = blockIdx.z;
    int b = z >> 1, isK = z & 1;
    int m = threadIdx.x;
    const float scale = 0.35355339059327373f;  // 64^-0.25
    __shared__ float xr[64];
    size_t base = ((size_t)b * SS + s) * (3 * DD) + (isK ? DD : 0) + h * DHH;
    xr[m] = qkv[base + m] * scale;
    __syncthreads();
    float proj = 0.f, sqv = 0.f;
    const float* w = wfeat + m * DHH;
    #pragma unroll 8
    for (int d = 0; d < DHH; d++) {
        float xv = xr[d];
        proj += xv * w[d];
        sqv += xv * xv;
    }
    float val = __expf(proj - 0.5f * sqv) * 0.125f + EPS_PHI;
    float* dst = isK ? phik : phiq;
    dst[((size_t)(b * HH + h) * SS + s) * MM + m] = val;
}

// ---------------------------------------------------------------------------
// Causal linear-attention scan. One wave (64 threads) per (b,h).
// Lane d owns state column st[m][d] (m=0..63) in registers; kd = cumsum phi_k[d].
// Inclusive order: state += phi_k[s] (x) v[s]  BEFORE  num = phi_q[s] . state.
// Output written head-merged: attn[b, s, h*64 + d].
// ---------------------------------------------------------------------------
__global__ __launch_bounds__(64) void scan_kernel(const float* __restrict__ phiq,
                                                  const float* __restrict__ phik,
                                                  const float* __restrict__ qkv,
                                                  float* __restrict__ attn) {
    int h = blockIdx.x, b = blockIdx.y;
    int bh = b * HH + h;
    int d = threadIdx.x;
    __shared__ float sq[64][64], sk[64][64], sv[64][64];
    float st[64];
    #pragma unroll
    for (int i = 0; i < 64; i++) st[i] = 0.f;
    float kd = 0.f;
    const float* pq = phiq + (size_t)bh * SS * MM;
    const float* pk = phik + (size_t)bh * SS * MM;
    for (int s0 = 0; s0 < SS; s0 += 64) {
        for (int i = 0; i < 64; i++) {
            sq[i][d] = pq[(size_t)(s0 + i) * MM + d];
            sk[i][d] = pk[(size_t)(s0 + i) * MM + d];
            sv[i][d] = qkv[((size_t)b * SS + s0 + i) * (3 * DD) + 2 * DD + h * DHH + d];
        }
        __syncthreads();
        for (int s = 0; s < 64; s++) {
            float vd = sv[s][d];
            const float4* k4 = (const float4*)&sk[s][0];
            const float4* q4 = (const float4*)&sq[s][0];
            #pragma unroll
            for (int m = 0; m < 16; m++) {
                float4 kv = k4[m];
                st[4 * m]     += kv.x * vd;
                st[4 * m + 1] += kv.y * vd;
                st[4 * m + 2] += kv.z * vd;
                st[4 * m + 3] += kv.w * vd;
            }
            float num = 0.f;
            #pragma unroll
            for (int m = 0; m < 16; m++) {
                float4 qv = q4[m];
                num += qv.x * st[4 * m] + qv.y * st[4 * m + 1]
                     + qv.z * st[4 * m + 2] + qv.w * st[4 * m + 3];
            }
            kd += sk[s][d];
            float den = sq[s][d] * kd;
            #pragma unroll
            for (int off = 32; off > 0; off >>= 1) den += __shfl_xor(den, off, 64);
            attn[((size_t)b * SS + s0 + s) * DD + h * DHH + d] = num / den;
        }
        __syncthreads();
    }
}

// ---------------------------------------------------------------------------
extern "C" void kernel_launch(void* const* d_in, const int* in_sizes, int n_in,
                              void* d_out, int out_size, void* d_ws, size_t ws_size,
                              hipStream_t stream) {
    const float* x      = (const float*)d_in[0];
    const float* ln1_g  = (const float*)d_in[1];
    const float* ln1_b  = (const float*)d_in[2];
    const float* w_attn = (const float*)d_in[3];
    const float* b_attn = (const float*)d_in[4];
    const float* w_feat = (const float*)d_in[5];
    const float* w_proj = (const float*)d_in[6];
    const float* b_proj = (const float*)d_in[7];
    const float* ln2_g  = (const float*)d_in[8];
    const float* ln2_b  = (const float*)d_in[9];
    const float* w_fc   = (const float*)d_in[10];
    const float* b_fc   = (const float*)d_in[11];
    const float* w_out  = (const float*)d_in[12];
    const float* b_out  = (const float*)d_in[13];
    float* out = (float*)d_out;

    float* ws = (float*)d_ws;
    size_t off = 0;
    float* buf_a    = ws + off; off += (size_t)BS * DD;        // LN1 out, reused for LN2 out
    float* buf_qkv  = ws + off; off += (size_t)BS * 3 * DD;    // 4.72M floats
    float* buf_phiq = ws + off; off += (size_t)BB * HH * SS * MM;  // 1.57M
    float* buf_phik = ws + off; off += (size_t)BB * HH * SS * MM;
    float* buf_attn = ws + off; off += (size_t)BS * DD;
    float* buf_x1   = ws + off; off += (size_t)BS * DD;
    // buf_fc (BS*DFF = 6.29M floats) aliases buf_qkv+buf_phiq (4.72M+1.57M = 6.29M):
    // qkv/phi are dead after step 5. Keeps peak ws at ~50 MB.
    float* buf_fc   = buf_qkv;

    // 1) a = LN1(x)
    ln_kernel<<<BS, 256, 0, stream>>>(x, ln1_g, ln1_b, buf_a);
    // 2) qkv = a @ w_attn + b_attn
    gemm_kernel<0, false><<<dim3(3 * DD / 64, BS / 64), 256, 0, stream>>>(
        buf_a, w_attn, b_attn, nullptr, buf_qkv, BS, 3 * DD, DD);
    // 3) phi features
    phi_kernel<<<dim3(SS, HH, 2 * BB), 64, 0, stream>>>(buf_qkv, w_feat, buf_phiq, buf_phik);
    // 4) causal linear-attention scan -> head-merged attn
    scan_kernel<<<dim3(HH, BB), 64, 0, stream>>>(buf_phiq, buf_phik, buf_qkv, buf_attn);
    // 5) x1 = x + attn @ w_proj + b_proj
    gemm_kernel<0, true><<<dim3(DD / 64, BS / 64), 256, 0, stream>>>(
        buf_attn, w_proj, b_proj, x, buf_x1, BS, DD, DD);
    // 6) m = LN2(x1)  (reuse buf_a)
    ln_kernel<<<BS, 256, 0, stream>>>(buf_x1, ln2_g, ln2_b, buf_a);
    // 7) fc = gelu(m @ w_fc + b_fc)   (buf_fc aliases dead qkv/phiq region)
    gemm_kernel<1, false><<<dim3(DFF / 64, BS / 64), 256, 0, stream>>>(
        buf_a, w_fc, b_fc, nullptr, buf_fc, BS, DFF, DD);
    // 8) out = x1 + fc @ w_out + b_out
    gemm_kernel<0, true><<<dim3(DD / 64, BS / 64), 256, 0, stream>>>(
        buf_fc, w_out, b_out, buf_x1, out, BS, DD, DFF);
}

// Round 6
// 392.173 us; speedup vs baseline: 3.6135x; 3.6135x over previous
//
#include <hip/hip_runtime.h>
#include <hip/hip_bf16.h>
#include <math.h>

// Problem constants
#define BB 2
#define SS 1024
#define DD 768
#define HH 12
#define DHH 64
#define MM 64
#define DFF 3072
#define BS (BB*SS)          // 2048 rows
#define EPS_LN 1e-5f
#define EPS_PHI 1e-6f
#define CC 64               // scan chunk length
#define NC (SS/CC)          // 16 chunks

typedef __hip_bfloat16 bf16;
using v8s = __attribute__((ext_vector_type(8))) short;   // 8 bf16 = 4 VGPRs (MFMA A/B frag)
using v4f = __attribute__((ext_vector_type(4))) float;   // MFMA C/D frag

// ---------------------------------------------------------------------------
// Transpose + cast: in f32 [K x N] row-major -> out bf16 [N x K] row-major.
// 32x32 LDS tiles, fully coalesced both sides.
// ---------------------------------------------------------------------------
__global__ __launch_bounds__(256) void transpose_cast_kernel(const float* __restrict__ in,
                                                             bf16* __restrict__ out,
                                                             int K, int N) {
    __shared__ float t[32][33];
    int tx = threadIdx.x, ty = threadIdx.y;        // 32 x 8
    int n0 = blockIdx.x * 32, k0 = blockIdx.y * 32;
    #pragma unroll
    for (int i = ty; i < 32; i += 8)
        t[i][tx] = in[(size_t)(k0 + i) * N + n0 + tx];
    __syncthreads();
    #pragma unroll
    for (int i = ty; i < 32; i += 8)
        out[(size_t)(n0 + i) * K + k0 + tx] = __float2bfloat16(t[tx][i]);
}

// ---------------------------------------------------------------------------
// LayerNorm: one block per row, 256 threads, D=768 -> 3 elems/thread.
// f32 in -> bf16 out (feeds MFMA GEMMs).
// ---------------------------------------------------------------------------
__global__ __launch_bounds__(256) void ln_kernel(const float* __restrict__ x,
                                                 const float* __restrict__ g,
                                                 const float* __restrict__ bta,
                                                 bf16* __restrict__ out) {
    int row = blockIdx.x;
    int t = threadIdx.x;
    const float* xr = x + (size_t)row * DD;
    float v0 = xr[t], v1 = xr[t + 256], v2 = xr[t + 512];
    float s = v0 + v1 + v2;
    float s2 = v0 * v0 + v1 * v1 + v2 * v2;
    #pragma unroll
    for (int off = 32; off > 0; off >>= 1) {
        s  += __shfl_xor(s,  off, 64);
        s2 += __shfl_xor(s2, off, 64);
    }
    __shared__ float ls[4], ls2[4];
    if ((t & 63) == 0) { ls[t >> 6] = s; ls2[t >> 6] = s2; }
    __syncthreads();
    s  = ls[0] + ls[1] + ls[2] + ls[3];
    s2 = ls2[0] + ls2[1] + ls2[2] + ls2[3];
    float mu  = s * (1.0f / DD);
    float var = s2 * (1.0f / DD) - mu * mu;
    float r = rsqrtf(var + EPS_LN);
    bf16* orow = out + (size_t)row * DD;
    orow[t]       = __float2bfloat16((v0 - mu) * r * g[t]       + bta[t]);
    orow[t + 256] = __float2bfloat16((v1 - mu) * r * g[t + 256] + bta[t + 256]);
    orow[t + 512] = __float2bfloat16((v2 - mu) * r * g[t + 512] + bta[t + 512]);
}

// ---------------------------------------------------------------------------
// MFMA GEMM: C[2048 x N] = A[2048 x K](bf16) @ BT[N x K](bf16)^T
//            + bias (+gelu) (+f32 residual); C f32 or bf16.
// 64x64 tile, BK=32, 256 thr = 4 waves; wave w owns rows [w*16, w*16+16).
// mfma_f32_16x16x32_bf16: A-frag A[m=lane&15][k=(lane>>4)*8+j] (verified m120);
// C/D: col=lane&15, row=(lane>>4)*4+reg (verified m89/m91).
// ---------------------------------------------------------------------------
__device__ inline float gelu_tanh(float x) {
    float x3 = x * x * x;
    float u = 0.7978845608028654f * (x + 0.044715f * x3);
    return 0.5f * x * (1.0f + tanhf(u));
}

template <int ACT, int HAS_RES, int OUT_BF16>
__global__ __launch_bounds__(256) void gemm_mfma_kernel(const bf16* __restrict__ A,
                                                        const bf16* __restrict__ BT,
                                                        const float* __restrict__ bias,
                                                        const float* __restrict__ res,
                                                        void* __restrict__ Cout,
                                                        int N, int K) {
    __shared__ bf16 Asl[64][40];   // row stride 80B (16B-aligned, 2-way-max banks)
    __shared__ bf16 Bsl[64][40];
    int tid = threadIdx.x;
    int m0 = blockIdx.y * 64, n0 = blockIdx.x * 64;
    int wave = tid >> 6, lane = tid & 63;
    int qm = lane & 15, quad = lane >> 4;

    // staging indices: each thread one 16B chunk of A-tile and B-tile
    int sm = tid >> 2, sk = (tid & 3) * 8;   // 64 rows x 32 cols

    v4f acc[4] = {{0.f,0.f,0.f,0.f},{0.f,0.f,0.f,0.f},{0.f,0.f,0.f,0.f},{0.f,0.f,0.f,0.f}};

    for (int k0 = 0; k0 < K; k0 += 32) {
        uint4 av = *(const uint4*)(A  + (size_t)(m0 + sm) * K + k0 + sk);
        uint4 bv = *(const uint4*)(BT + (size_t)(n0 + sm) * K + k0 + sk);
        __syncthreads();
        *(uint4*)&Asl[sm][sk] = av;
        *(uint4*)&Bsl[sm][sk] = bv;
        __syncthreads();
        v8s a = *(const v8s*)&Asl[wave * 16 + qm][quad * 8];
        #pragma unroll
        for (int t = 0; t < 4; t++) {
            v8s b = *(const v8s*)&Bsl[t * 16 + qm][quad * 8];
            acc[t] = __builtin_amdgcn_mfma_f32_16x16x32_bf16(a, b, acc[t], 0, 0, 0);
        }
    }

    int col_l = lane & 15;
    #pragma unroll
    for (int t = 0; t < 4; t++) {
        int col = n0 + t * 16 + col_l;
        float bcol = bias[col];
        #pragma unroll
        for (int r = 0; r < 4; r++) {
            int row = m0 + wave * 16 + quad * 4 + r;
            float v = acc[t][r] + bcol;
            if (ACT == 1) v = gelu_tanh(v);
            if (HAS_RES) v += res[(size_t)row * N + col];
            if (OUT_BF16) ((bf16*)Cout)[(size_t)row * N + col] = __float2bfloat16(v);
            else          ((float*)Cout)[(size_t)row * N + col] = v;
        }
    }
}

// ---------------------------------------------------------------------------
// FAVOR+ features: phi = exp(proj - 0.5*||x||^2) / sqrt(M) + eps  (f32)
// ---------------------------------------------------------------------------
__global__ __launch_bounds__(64) void phi_kernel(const float* __restrict__ qkv,
                                                 const float* __restrict__ wfeat,
                                                 float* __restrict__ phiq,
                                                 float* __restrict__ phik) {
    int s = blockIdx.x, h = blockIdx.y, z = blockIdx.z;
    int b = z >> 1, isK = z & 1;
    int m = threadIdx.x;
    const float scale = 0.35355339059327373f;  // 64^-0.25
    __shared__ float xr[64];
    size_t base = ((size_t)b * SS + s) * (3 * DD) + (isK ? DD : 0) + h * DHH;
    xr[m] = qkv[base + m] * scale;
    __syncthreads();
    float proj = 0.f, sqv = 0.f;
    const float* w = wfeat + m * DHH;
    #pragma unroll 8
    for (int d = 0; d < DHH; d++) {
        float xv = xr[d];
        proj += xv * w[d];
        sqv += xv * xv;
    }
    float val = __expf(proj - 0.5f * sqv) * 0.125f + EPS_PHI;
    float* dst = isK ? phik : phiq;
    dst[((size_t)(b * HH + h) * SS + s) * MM + m] = val;
}

// ---------------------------------------------------------------------------
// Scan phase 1: per-chunk sums. grid (NC, H, B), 64 threads (lane = d, also m).
// ---------------------------------------------------------------------------
__global__ __launch_bounds__(64) void scan_sums_kernel(const float* __restrict__ phik,
                                                       const float* __restrict__ qkv,
                                                       float* __restrict__ Skv,
                                                       float* __restrict__ Sk) {
    int c = blockIdx.x, h = blockIdx.y, b = blockIdx.z;
    int bh = b * HH + h;
    int d = threadIdx.x;
    __shared__ float sk[CC][64], sv[CC][64];
    const float* pk = phik + (size_t)bh * SS * MM;
    for (int i = 0; i < CC; i++) {
        sk[i][d] = pk[(size_t)(c * CC + i) * MM + d];
        sv[i][d] = qkv[((size_t)b * SS + c * CC + i) * (3 * DD) + 2 * DD + h * DHH + d];
    }
    __syncthreads();
    float st[64];
    #pragma unroll
    for (int i = 0; i < 64; i++) st[i] = 0.f;
    for (int s = 0; s < CC; s++) {
        float vd = sv[s][d];
        const float4* k4 = (const float4*)&sk[s][0];
        #pragma unroll
        for (int m = 0; m < 16; m++) {
            float4 kv = k4[m];
            st[4 * m]     += kv.x * vd;
            st[4 * m + 1] += kv.y * vd;
            st[4 * m + 2] += kv.z * vd;
            st[4 * m + 3] += kv.w * vd;
        }
    }
    float* dst = Skv + ((size_t)bh * NC + c) * 64 * 64;
    #pragma unroll
    for (int m = 0; m < 64; m++) dst[m * 64 + d] = st[m];
    float acc = 0.f;
    for (int s = 0; s < CC; s++) acc += sk[s][d];
    Sk[((size_t)bh * NC + c) * 64 + d] = acc;
}

// ---------------------------------------------------------------------------
// Scan phase 2: in-place EXCLUSIVE prefix over chunks.
// ---------------------------------------------------------------------------
__global__ __launch_bounds__(256) void scan_prefix_kernel(float* __restrict__ Skv,
                                                          float* __restrict__ Sk) {
    int bh = blockIdx.y;
    int t = blockIdx.x * 256 + threadIdx.x;   // 0..4095 = m*64+d
    size_t base = (size_t)bh * NC * 4096 + t;
    float acc = 0.f;
    for (int c = 0; c < NC; c++) {
        float v = Skv[base + (size_t)c * 4096];
        Skv[base + (size_t)c * 4096] = acc;
        acc += v;
    }
    if (blockIdx.x == 0 && threadIdx.x < 64) {
        size_t b2 = (size_t)bh * NC * 64 + threadIdx.x;
        float a2 = 0.f;
        for (int c = 0; c < NC; c++) {
            float v = Sk[b2 + (size_t)c * 64];
            Sk[b2 + (size_t)c * 64] = a2;
            a2 += v;
        }
    }
}

// ---------------------------------------------------------------------------
// Scan phase 3: per-chunk inclusive scan from prefix state -> attn (bf16).
// ---------------------------------------------------------------------------
__global__ __launch_bounds__(64) void scan_chunk_kernel(const float* __restrict__ phiq,
                                                        const float* __restrict__ phik,
                                                        const float* __restrict__ qkv,
                                                        const float* __restrict__ Pstate,
                                                        const float* __restrict__ SkPre,
                                                        bf16* __restrict__ attn) {
    int c = blockIdx.x, h = blockIdx.y, b = blockIdx.z;
    int bh = b * HH + h;
    int d = threadIdx.x;
    __shared__ float sq[CC][64], sk[CC][64], sv[CC][64];
    const float* pq = phiq + (size_t)bh * SS * MM;
    const float* pk = phik + (size_t)bh * SS * MM;
    for (int i = 0; i < CC; i++) {
        sq[i][d] = pq[(size_t)(c * CC + i) * MM + d];
        sk[i][d] = pk[(size_t)(c * CC + i) * MM + d];
        sv[i][d] = qkv[((size_t)b * SS + c * CC + i) * (3 * DD) + 2 * DD + h * DHH + d];
    }
    float st[64];
    const float* ps = Pstate + ((size_t)bh * NC + c) * 4096;
    #pragma unroll
    for (int m = 0; m < 64; m++) st[m] = ps[m * 64 + d];
    float kd = SkPre[((size_t)bh * NC + c) * 64 + d];
    __syncthreads();
    for (int s = 0; s < CC; s++) {
        float vd = sv[s][d];
        const float4* k4 = (const float4*)&sk[s][0];
        const float4* q4 = (const float4*)&sq[s][0];
        #pragma unroll
        for (int m = 0; m < 16; m++) {
            float4 kv = k4[m];
            st[4 * m]     += kv.x * vd;
            st[4 * m + 1] += kv.y * vd;
            st[4 * m + 2] += kv.z * vd;
            st[4 * m + 3] += kv.w * vd;
        }
        float num = 0.f;
        #pragma unroll
        for (int m = 0; m < 16; m++) {
            float4 qv = q4[m];
            num += qv.x * st[4 * m] + qv.y * st[4 * m + 1]
                 + qv.z * st[4 * m + 2] + qv.w * st[4 * m + 3];
        }
        kd += sk[s][d];
        float den = sq[s][d] * kd;
        #pragma unroll
        for (int off = 32; off > 0; off >>= 1) den += __shfl_xor(den, off, 64);
        attn[((size_t)b * SS + c * CC + s) * DD + h * DHH + d] = __float2bfloat16(num / den);
    }
}

// ---------------------------------------------------------------------------
extern "C" void kernel_launch(void* const* d_in, const int* in_sizes, int n_in,
                              void* d_out, int out_size, void* d_ws, size_t ws_size,
                              hipStream_t stream) {
    const float* x      = (const float*)d_in[0];
    const float* ln1_g  = (const float*)d_in[1];
    const float* ln1_b  = (const float*)d_in[2];
    const float* w_attn = (const float*)d_in[3];
    const float* b_attn = (const float*)d_in[4];
    const float* w_feat = (const float*)d_in[5];
    const float* w_proj = (const float*)d_in[6];
    const float* b_proj = (const float*)d_in[7];
    const float* ln2_g  = (const float*)d_in[8];
    const float* ln2_b  = (const float*)d_in[9];
    const float* w_fc   = (const float*)d_in[10];
    const float* b_fc   = (const float*)d_in[11];
    const float* w_out  = (const float*)d_in[12];
    const float* b_out  = (const float*)d_in[13];
    float* out = (float*)d_out;

    // f32 region
    float* ws = (float*)d_ws;
    size_t off = 0;
    float* buf_qkv  = ws + off; off += (size_t)BS * 3 * DD;        // 4.72M f32
    float* buf_phiq = ws + off; off += (size_t)BB * HH * SS * MM;  // 1.57M
    float* buf_phik = ws + off; off += (size_t)BB * HH * SS * MM;  // 1.57M
    float* buf_x1   = ws + off; off += (size_t)BS * DD;            // 1.57M
    float* buf_sk   = ws + off; off += (size_t)BB * HH * NC * MM;  // 24.6K
    // bf16 region (starts 16B-aligned: all preceding sizes are multiples of 4 elems)
    bf16* wb = (bf16*)(ws + off);
    size_t boff = 0;
    bf16* buf_a_bf    = wb + boff; boff += (size_t)BS * DD;        // LN out
    bf16* buf_attn_bf = wb + boff; boff += (size_t)BS * DD;
    bf16* wattn_t     = wb + boff; boff += (size_t)3 * DD * DD;    // [2304 x 768]
    bf16* wproj_t     = wb + boff; boff += (size_t)DD * DD;        // [768 x 768]
    bf16* wfc_t       = wb + boff; boff += (size_t)DFF * DD;       // [3072 x 768]
    bf16* wout_t      = wb + boff; boff += (size_t)DD * DFF;       // [768 x 3072]
    // Aliases:
    //  - Skv (24*16*4096 = 1.57M f32) over buf_x1: x1 written only after scan.
    //  - fc bf16 (BS*DFF = 6.29M bf16 = 12.58MB) over phiq+phik (3.15M f32
    //    = 12.58MB): phi dead after scan phase 3; fc written in step 7.
    float* buf_skv  = buf_x1;
    bf16*  buf_fc_bf = (bf16*)buf_phiq;

    // 0) weights -> bf16 transposed [N x K]
    transpose_cast_kernel<<<dim3(3 * DD / 32, DD / 32), dim3(32, 8), 0, stream>>>(w_attn, wattn_t, DD, 3 * DD);
    transpose_cast_kernel<<<dim3(DD / 32, DD / 32),     dim3(32, 8), 0, stream>>>(w_proj, wproj_t, DD, DD);
    transpose_cast_kernel<<<dim3(DFF / 32, DD / 32),    dim3(32, 8), 0, stream>>>(w_fc,   wfc_t,   DD, DFF);
    transpose_cast_kernel<<<dim3(DD / 32, DFF / 32),    dim3(32, 8), 0, stream>>>(w_out,  wout_t,  DFF, DD);

    // 1) a = LN1(x) -> bf16
    ln_kernel<<<BS, 256, 0, stream>>>(x, ln1_g, ln1_b, buf_a_bf);
    // 2) qkv = a @ w_attn + b_attn  (f32 out, feeds phi/scan)
    gemm_mfma_kernel<0, 0, 0><<<dim3(3 * DD / 64, BS / 64), 256, 0, stream>>>(
        buf_a_bf, wattn_t, b_attn, nullptr, buf_qkv, 3 * DD, DD);
    // 3) phi features (f32)
    phi_kernel<<<dim3(SS, HH, 2 * BB), 64, 0, stream>>>(buf_qkv, w_feat, buf_phiq, buf_phik);
    // 4a) per-chunk sums
    scan_sums_kernel<<<dim3(NC, HH, BB), 64, 0, stream>>>(buf_phik, buf_qkv, buf_skv, buf_sk);
    // 4b) exclusive prefix over chunks (in place)
    scan_prefix_kernel<<<dim3(4096 / 256, BB * HH), 256, 0, stream>>>(buf_skv, buf_sk);
    // 4c) per-chunk scan -> attn (bf16)
    scan_chunk_kernel<<<dim3(NC, HH, BB), 64, 0, stream>>>(
        buf_phiq, buf_phik, buf_qkv, buf_skv, buf_sk, buf_attn_bf);
    // 5) x1 = x + attn @ w_proj + b_proj  (f32 out; overwrites Skv region)
    gemm_mfma_kernel<0, 1, 0><<<dim3(DD / 64, BS / 64), 256, 0, stream>>>(
        buf_attn_bf, wproj_t, b_proj, x, buf_x1, DD, DD);
    // 6) m = LN2(x1) -> bf16
    ln_kernel<<<BS, 256, 0, stream>>>(buf_x1, ln2_g, ln2_b, buf_a_bf);
    // 7) fc = gelu(m @ w_fc + b_fc) -> bf16 (aliases dead phi region)
    gemm_mfma_kernel<1, 0, 1><<<dim3(DFF / 64, BS / 64), 256, 0, stream>>>(
        buf_a_bf, wfc_t, b_fc, nullptr, buf_fc_bf, DFF, DD);
    // 8) out = x1 + fc @ w_out + b_out (f32)
    gemm_mfma_kernel<0, 1, 0><<<dim3(DD / 64, BS / 64), 256, 0, stream>>>(
        buf_fc_bf, wout_t, b_out, buf_x1, out, DD, DFF);
}

// Round 7
// 343.080 us; speedup vs baseline: 4.1306x; 1.1431x over previous
//
#include <hip/hip_runtime.h>
#include <hip/hip_bf16.h>
#include <math.h>

// Problem constants
#define BB 2
#define SS 1024
#define DD 768
#define HH 12
#define DHH 64
#define MM 64
#define DFF 3072
#define BS (BB*SS)          // 2048 rows
#define EPS_LN 1e-5f
#define EPS_PHI 1e-6f
#define CC 64               // scan chunk length
#define NC (SS/CC)          // 16 chunks
#define NQ 3840             // extended qkv width: q,k,v (2304) + proj_q (768) + proj_k (768)
#define PQOFF 2304          // proj_q column base
#define PKOFF 3072          // proj_k column base
#define VOFF  1536          // v column base

typedef __hip_bfloat16 bf16;
using v8s = __attribute__((ext_vector_type(8))) short;   // 8 bf16 = 4 VGPRs (MFMA A/B frag)
using v4f = __attribute__((ext_vector_type(4))) float;   // MFMA C/D frag

// ---------------------------------------------------------------------------
// Transpose + cast: in f32 [K x N] row-major -> out bf16 [N x K] row-major.
// ---------------------------------------------------------------------------
__global__ __launch_bounds__(256) void transpose_cast_kernel(const float* __restrict__ in,
                                                             bf16* __restrict__ out,
                                                             int K, int N) {
    __shared__ float t[32][33];
    int tx = threadIdx.x, ty = threadIdx.y;        // 32 x 8
    int n0 = blockIdx.x * 32, k0 = blockIdx.y * 32;
    #pragma unroll
    for (int i = ty; i < 32; i += 8)
        t[i][tx] = in[(size_t)(k0 + i) * N + n0 + tx];
    __syncthreads();
    #pragma unroll
    for (int i = ty; i < 32; i += 8)
        out[(size_t)(n0 + i) * K + k0 + tx] = __float2bfloat16(t[tx][i]);
}

// ---------------------------------------------------------------------------
// Fused FAVOR+ projection weights:
//   BT_ext[2304 + isK*768 + h*64 + m][j] = scale * sum_d W[j][isK*768+h*64+d] * wf[m][d]
//   bias_ext[2304 + ...] = scale * sum_d b_attn[...+d] * wf[m][d]
// grid (12 jtiles, H, 2), 256 threads. wf and W tiles staged in LDS (padded).
// ---------------------------------------------------------------------------
__global__ __launch_bounds__(256) void fuse_feat_kernel(const float* __restrict__ w_attn,
                                                        const float* __restrict__ b_attn,
                                                        const float* __restrict__ wfeat,
                                                        bf16* __restrict__ bt_ext,
                                                        float* __restrict__ bias_ext) {
    __shared__ float wfT[64][65];   // wfT[d][m] = scale*wf[m][d]
    __shared__ float Wt[64][65];    // Wt[j][d]
    int t = threadIdx.x;
    int j0 = blockIdx.x * 64, h = blockIdx.y, isK = blockIdx.z;
    int base = isK * DD + h * DHH;
    const float scale = 0.35355339059327373f;  // 64^-0.25
    #pragma unroll
    for (int it = 0; it < 16; it++) {
        int idx = it * 256 + t;
        int m = idx >> 6, d = idx & 63;
        wfT[d][m] = scale * wfeat[m * DHH + d];
        Wt[idx >> 6][idx & 63] = w_attn[(size_t)(j0 + (idx >> 6)) * (3 * DD) + base + (idx & 63)];
    }
    __syncthreads();
    int jl = t & 63, mg = (t >> 6) * 16;
    for (int m = mg; m < mg + 16; m++) {
        float acc = 0.f;
        #pragma unroll 8
        for (int d = 0; d < 64; d++) acc += wfT[d][m] * Wt[jl][d];
        bt_ext[(size_t)(PQOFF + isK * DD + h * DHH + m) * DD + j0 + jl] = __float2bfloat16(acc);
    }
    if (blockIdx.x == 0 && t < 64) {
        float accb = 0.f;
        #pragma unroll 8
        for (int d = 0; d < 64; d++) accb += wfT[d][t] * b_attn[base + d];
        bias_ext[PQOFF + isK * DD + h * DHH + t] = accb;
    }
}

// ---------------------------------------------------------------------------
// LayerNorm: one block per row, 256 threads; f32 in -> bf16 out.
// ---------------------------------------------------------------------------
__global__ __launch_bounds__(256) void ln_kernel(const float* __restrict__ x,
                                                 const float* __restrict__ g,
                                                 const float* __restrict__ bta,
                                                 bf16* __restrict__ out) {
    int row = blockIdx.x;
    int t = threadIdx.x;
    const float* xr = x + (size_t)row * DD;
    float v0 = xr[t], v1 = xr[t + 256], v2 = xr[t + 512];
    float s = v0 + v1 + v2;
    float s2 = v0 * v0 + v1 * v1 + v2 * v2;
    #pragma unroll
    for (int off = 32; off > 0; off >>= 1) {
        s  += __shfl_xor(s,  off, 64);
        s2 += __shfl_xor(s2, off, 64);
    }
    __shared__ float ls[4], ls2[4];
    if ((t & 63) == 0) { ls[t >> 6] = s; ls2[t >> 6] = s2; }
    __syncthreads();
    s  = ls[0] + ls[1] + ls[2] + ls[3];
    s2 = ls2[0] + ls2[1] + ls2[2] + ls2[3];
    float mu  = s * (1.0f / DD);
    float var = s2 * (1.0f / DD) - mu * mu;
    float r = rsqrtf(var + EPS_LN);
    bf16* orow = out + (size_t)row * DD;
    orow[t]       = __float2bfloat16((v0 - mu) * r * g[t]       + bta[t]);
    orow[t + 256] = __float2bfloat16((v1 - mu) * r * g[t + 256] + bta[t + 256]);
    orow[t + 512] = __float2bfloat16((v2 - mu) * r * g[t + 512] + bta[t + 512]);
}

// ---------------------------------------------------------------------------
// MFMA GEMM: C[2048 x N] = A[2048 x K](bf16) @ BT[N x K](bf16)^T
//            + bias (+gelu) (+f32 residual); C f32 or bf16.
// 64x64 tile, BK=32, 4 waves; verified fragment layouts (m120, m89/m91).
// ---------------------------------------------------------------------------
__device__ inline float gelu_tanh(float x) {
    float x3 = x * x * x;
    float u = 0.7978845608028654f * (x + 0.044715f * x3);
    return 0.5f * x * (1.0f + tanhf(u));
}

template <int ACT, int HAS_RES, int OUT_BF16>
__global__ __launch_bounds__(256) void gemm_mfma_kernel(const bf16* __restrict__ A,
                                                        const bf16* __restrict__ BT,
                                                        const float* __restrict__ bias,
                                                        const float* __restrict__ res,
                                                        void* __restrict__ Cout,
                                                        int N, int K) {
    __shared__ bf16 Asl[64][40];
    __shared__ bf16 Bsl[64][40];
    int tid = threadIdx.x;
    int m0 = blockIdx.y * 64, n0 = blockIdx.x * 64;
    int wave = tid >> 6, lane = tid & 63;
    int qm = lane & 15, quad = lane >> 4;
    int sm = tid >> 2, sk = (tid & 3) * 8;

    v4f acc[4] = {{0.f,0.f,0.f,0.f},{0.f,0.f,0.f,0.f},{0.f,0.f,0.f,0.f},{0.f,0.f,0.f,0.f}};

    for (int k0 = 0; k0 < K; k0 += 32) {
        uint4 av = *(const uint4*)(A  + (size_t)(m0 + sm) * K + k0 + sk);
        uint4 bv = *(const uint4*)(BT + (size_t)(n0 + sm) * K + k0 + sk);
        __syncthreads();
        *(uint4*)&Asl[sm][sk] = av;
        *(uint4*)&Bsl[sm][sk] = bv;
        __syncthreads();
        v8s a = *(const v8s*)&Asl[wave * 16 + qm][quad * 8];
        #pragma unroll
        for (int t = 0; t < 4; t++) {
            v8s b = *(const v8s*)&Bsl[t * 16 + qm][quad * 8];
            acc[t] = __builtin_amdgcn_mfma_f32_16x16x32_bf16(a, b, acc[t], 0, 0, 0);
        }
    }

    int col_l = lane & 15;
    #pragma unroll
    for (int t = 0; t < 4; t++) {
        int col = n0 + t * 16 + col_l;
        float bcol = bias[col];
        #pragma unroll
        for (int r = 0; r < 4; r++) {
            int row = m0 + wave * 16 + quad * 4 + r;
            float v = acc[t][r] + bcol;
            if (ACT == 1) v = gelu_tanh(v);
            if (HAS_RES) v += res[(size_t)row * N + col];
            if (OUT_BF16) ((bf16*)Cout)[(size_t)row * N + col] = __float2bfloat16(v);
            else          ((float*)Cout)[(size_t)row * N + col] = v;
        }
    }
}

// ---------------------------------------------------------------------------
// phi in place: qkvp[row, PQOFF/PKOFF + h*64 + m] = exp(proj - ||q_s||^2/2) / 8 + eps
// where proj already includes the DH^-1/4 scale (fused weights) and
// sq = 0.5*scale^2*sum_d q^2 = sum_d q^2 / 16.
// grid (S, 3, 2B): h = blockIdx.y*4 + (t>>6), one wave per (s,h,isK).
// ---------------------------------------------------------------------------
__global__ __launch_bounds__(256) void phi_exp_kernel(float* __restrict__ qkvp) {
    int s = blockIdx.x, z = blockIdx.z;
    int b = z >> 1, isK = z & 1;
    int t = threadIdx.x;
    int h = blockIdx.y * 4 + (t >> 6);
    int m = t & 63;
    size_t row = (size_t)b * SS + s;
    float qd = qkvp[row * NQ + isK * DD + h * DHH + m];
    float sq = qd * qd;
    #pragma unroll
    for (int off = 32; off > 0; off >>= 1) sq += __shfl_xor(sq, off, 64);
    sq *= (1.0f / 16.0f);
    size_t pidx = row * NQ + PQOFF + isK * DD + h * DHH + m;
    float proj = qkvp[pidx];
    qkvp[pidx] = __expf(proj - sq) * 0.125f + EPS_PHI;
}

// ---------------------------------------------------------------------------
// Scan phase 1: per-chunk sums (phi_k, v read from extended qkvp).
// ---------------------------------------------------------------------------
__global__ __launch_bounds__(64) void scan_sums_kernel(const float* __restrict__ qkvp,
                                                       float* __restrict__ Skv,
                                                       float* __restrict__ Sk) {
    int c = blockIdx.x, h = blockIdx.y, b = blockIdx.z;
    int bh = b * HH + h;
    int d = threadIdx.x;
    __shared__ float sk[CC][64], sv[CC][64];
    for (int i = 0; i < CC; i++) {
        size_t row = (size_t)b * SS + c * CC + i;
        sk[i][d] = qkvp[row * NQ + PKOFF + h * DHH + d];
        sv[i][d] = qkvp[row * NQ + VOFF  + h * DHH + d];
    }
    __syncthreads();
    float st[64];
    #pragma unroll
    for (int i = 0; i < 64; i++) st[i] = 0.f;
    for (int s = 0; s < CC; s++) {
        float vd = sv[s][d];
        const float4* k4 = (const float4*)&sk[s][0];
        #pragma unroll
        for (int m = 0; m < 16; m++) {
            float4 kv = k4[m];
            st[4 * m]     += kv.x * vd;
            st[4 * m + 1] += kv.y * vd;
            st[4 * m + 2] += kv.z * vd;
            st[4 * m + 3] += kv.w * vd;
        }
    }
    float* dst = Skv + ((size_t)bh * NC + c) * 64 * 64;
    #pragma unroll
    for (int m = 0; m < 64; m++) dst[m * 64 + d] = st[m];
    float acc = 0.f;
    for (int s = 0; s < CC; s++) acc += sk[s][d];
    Sk[((size_t)bh * NC + c) * 64 + d] = acc;
}

// ---------------------------------------------------------------------------
// Scan phase 2: in-place EXCLUSIVE prefix over chunks.
// ---------------------------------------------------------------------------
__global__ __launch_bounds__(256) void scan_prefix_kernel(float* __restrict__ Skv,
                                                          float* __restrict__ Sk) {
    int bh = blockIdx.y;
    int t = blockIdx.x * 256 + threadIdx.x;   // 0..4095 = m*64+d
    size_t base = (size_t)bh * NC * 4096 + t;
    float acc = 0.f;
    for (int c = 0; c < NC; c++) {
        float v = Skv[base + (size_t)c * 4096];
        Skv[base + (size_t)c * 4096] = acc;
        acc += v;
    }
    if (blockIdx.x == 0 && threadIdx.x < 64) {
        size_t b2 = (size_t)bh * NC * 64 + threadIdx.x;
        float a2 = 0.f;
        for (int c = 0; c < NC; c++) {
            float v = Sk[b2 + (size_t)c * 64];
            Sk[b2 + (size_t)c * 64] = a2;
            a2 += v;
        }
    }
}

// ---------------------------------------------------------------------------
// Scan phase 3: per-chunk inclusive scan from prefix state -> attn (bf16).
// ---------------------------------------------------------------------------
__global__ __launch_bounds__(64) void scan_chunk_kernel(const float* __restrict__ qkvp,
                                                        const float* __restrict__ Pstate,
                                                        const float* __restrict__ SkPre,
                                                        bf16* __restrict__ attn) {
    int c = blockIdx.x, h = blockIdx.y, b = blockIdx.z;
    int bh = b * HH + h;
    int d = threadIdx.x;
    __shared__ float sq[CC][64], sk[CC][64], sv[CC][64];
    for (int i = 0; i < CC; i++) {
        size_t row = (size_t)b * SS + c * CC + i;
        sq[i][d] = qkvp[row * NQ + PQOFF + h * DHH + d];
        sk[i][d] = qkvp[row * NQ + PKOFF + h * DHH + d];
        sv[i][d] = qkvp[row * NQ + VOFF  + h * DHH + d];
    }
    float st[64];
    const float* ps = Pstate + ((size_t)bh * NC + c) * 4096;
    #pragma unroll
    for (int m = 0; m < 64; m++) st[m] = ps[m * 64 + d];
    float kd = SkPre[((size_t)bh * NC + c) * 64 + d];
    __syncthreads();
    for (int s = 0; s < CC; s++) {
        float vd = sv[s][d];
        const float4* k4 = (const float4*)&sk[s][0];
        const float4* q4 = (const float4*)&sq[s][0];
        #pragma unroll
        for (int m = 0; m < 16; m++) {
            float4 kv = k4[m];
            st[4 * m]     += kv.x * vd;
            st[4 * m + 1] += kv.y * vd;
            st[4 * m + 2] += kv.z * vd;
            st[4 * m + 3] += kv.w * vd;
        }
        float num = 0.f;
        #pragma unroll
        for (int m = 0; m < 16; m++) {
            float4 qv = q4[m];
            num += qv.x * st[4 * m] + qv.y * st[4 * m + 1]
                 + qv.z * st[4 * m + 2] + qv.w * st[4 * m + 3];
        }
        kd += sk[s][d];
        float den = sq[s][d] * kd;
        #pragma unroll
        for (int off = 32; off > 0; off >>= 1) den += __shfl_xor(den, off, 64);
        attn[((size_t)b * SS + c * CC + s) * DD + h * DHH + d] = __float2bfloat16(num / den);
    }
}

// ---------------------------------------------------------------------------
extern "C" void kernel_launch(void* const* d_in, const int* in_sizes, int n_in,
                              void* d_out, int out_size, void* d_ws, size_t ws_size,
                              hipStream_t stream) {
    const float* x      = (const float*)d_in[0];
    const float* ln1_g  = (const float*)d_in[1];
    const float* ln1_b  = (const float*)d_in[2];
    const float* w_attn = (const float*)d_in[3];
    const float* b_attn = (const float*)d_in[4];
    const float* w_feat = (const float*)d_in[5];
    const float* w_proj = (const float*)d_in[6];
    const float* b_proj = (const float*)d_in[7];
    const float* ln2_g  = (const float*)d_in[8];
    const float* ln2_b  = (const float*)d_in[9];
    const float* w_fc   = (const float*)d_in[10];
    const float* b_fc   = (const float*)d_in[11];
    const float* w_out  = (const float*)d_in[12];
    const float* b_out  = (const float*)d_in[13];
    float* out = (float*)d_out;

    // f32 region
    float* ws = (float*)d_ws;
    size_t off = 0;
    float* buf_qkvp = ws + off; off += (size_t)BS * NQ;            // 7.86M f32 (q,k,v,proj->phi)
    float* buf_x1   = ws + off; off += (size_t)BS * DD;            // 1.57M
    float* buf_sk   = ws + off; off += (size_t)BB * HH * NC * MM;  // 24.6K
    float* bias_ext = ws + off; off += NQ;                         // 3840
    // bf16 region (16B-aligned: preceding counts are multiples of 4)
    bf16* wb = (bf16*)(ws + off);
    size_t boff = 0;
    bf16* buf_a_bf    = wb + boff; boff += (size_t)BS * DD;        // LN out
    bf16* buf_attn_bf = wb + boff; boff += (size_t)BS * DD;
    bf16* wext_t      = wb + boff; boff += (size_t)NQ * DD;        // [3840 x 768]
    bf16* wproj_t     = wb + boff; boff += (size_t)DD * DD;
    bf16* wfc_t       = wb + boff; boff += (size_t)DFF * DD;
    bf16* wout_t      = wb + boff; boff += (size_t)DD * DFF;
    // Aliases:
    //  - Skv (1.57M f32) over buf_x1: x1 written only after scan completes.
    //  - fc bf16 (6.29M bf16 = 12.6MB) over buf_qkvp head: qkvp dead after 4c.
    float* buf_skv   = buf_x1;
    bf16*  buf_fc_bf = (bf16*)buf_qkvp;

    // 0) weight prep: transposes + fused FAVOR+ projection columns
    transpose_cast_kernel<<<dim3(3 * DD / 32, DD / 32), dim3(32, 8), 0, stream>>>(w_attn, wext_t, DD, 3 * DD);
    fuse_feat_kernel<<<dim3(DD / 64, HH, 2), 256, 0, stream>>>(w_attn, b_attn, w_feat, wext_t, bias_ext);
    hipMemcpyAsync(bias_ext, b_attn, 3 * DD * sizeof(float), hipMemcpyDeviceToDevice, stream);
    transpose_cast_kernel<<<dim3(DD / 32, DD / 32),  dim3(32, 8), 0, stream>>>(w_proj, wproj_t, DD, DD);
    transpose_cast_kernel<<<dim3(DFF / 32, DD / 32), dim3(32, 8), 0, stream>>>(w_fc,   wfc_t,   DD, DFF);
    transpose_cast_kernel<<<dim3(DD / 32, DFF / 32), dim3(32, 8), 0, stream>>>(w_out,  wout_t,  DFF, DD);

    // 1) a = LN1(x) -> bf16
    ln_kernel<<<BS, 256, 0, stream>>>(x, ln1_g, ln1_b, buf_a_bf);
    // 2) [qkv | proj_q | proj_k] = a @ W_ext + bias_ext  (f32, width 3840)
    gemm_mfma_kernel<0, 0, 0><<<dim3(NQ / 64, BS / 64), 256, 0, stream>>>(
        buf_a_bf, wext_t, bias_ext, nullptr, buf_qkvp, NQ, DD);
    // 3) phi in place over proj columns
    phi_exp_kernel<<<dim3(SS, 3, 2 * BB), 256, 0, stream>>>(buf_qkvp);
    // 4a) per-chunk sums
    scan_sums_kernel<<<dim3(NC, HH, BB), 64, 0, stream>>>(buf_qkvp, buf_skv, buf_sk);
    // 4b) exclusive prefix over chunks (in place)
    scan_prefix_kernel<<<dim3(4096 / 256, BB * HH), 256, 0, stream>>>(buf_skv, buf_sk);
    // 4c) per-chunk scan -> attn (bf16)
    scan_chunk_kernel<<<dim3(NC, HH, BB), 64, 0, stream>>>(
        buf_qkvp, buf_skv, buf_sk, buf_attn_bf);
    // 5) x1 = x + attn @ w_proj + b_proj  (f32; overwrites Skv region)
    gemm_mfma_kernel<0, 1, 0><<<dim3(DD / 64, BS / 64), 256, 0, stream>>>(
        buf_attn_bf, wproj_t, b_proj, x, buf_x1, DD, DD);
    // 6) m = LN2(x1) -> bf16
    ln_kernel<<<BS, 256, 0, stream>>>(buf_x1, ln2_g, ln2_b, buf_a_bf);
    // 7) fc = gelu(m @ w_fc + b_fc) -> bf16 (aliases dead qkvp region)
    gemm_mfma_kernel<1, 0, 1><<<dim3(DFF / 64, BS / 64), 256, 0, stream>>>(
        buf_a_bf, wfc_t, b_fc, nullptr, buf_fc_bf, DFF, DD);
    // 8) out = x1 + fc @ w_out + b_out (f32)
    gemm_mfma_kernel<0, 1, 0><<<dim3(DD / 64, BS / 64), 256, 0, stream>>>(
        buf_fc_bf, wout_t, b_out, buf_x1, out, DD, DFF);
}

// Round 8
// 287.163 us; speedup vs baseline: 4.9349x; 1.1947x over previous
//
#include <hip/hip_runtime.h>
#include <hip/hip_bf16.h>
#include <math.h>

// Problem constants
#define BB 2
#define SS 1024
#define DD 768
#define HH 12
#define DHH 64
#define MM 64
#define DFF 3072
#define BS (BB*SS)          // 2048 rows
#define EPS_LN 1e-5f
#define EPS_PHI 1e-6f
#define CC 64               // scan chunk length
#define NC (SS/CC)          // 16 chunks
#define NQ 3840             // q,k,v (2304) + proj_q (768) + proj_k (768)
#define PQOFF 2304
#define PKOFF 3072
#define VOFF  1536

typedef __hip_bfloat16 bf16;
using v8s = __attribute__((ext_vector_type(8))) short;   // 8 bf16 (MFMA A/B frag)
using v4f = __attribute__((ext_vector_type(4))) float;   // MFMA C/D frag

// ---------------------------------------------------------------------------
// Transpose + cast: in f32 [K x N] row-major -> out bf16 [N x K] row-major.
// ---------------------------------------------------------------------------
__global__ __launch_bounds__(256) void transpose_cast_kernel(const float* __restrict__ in,
                                                             bf16* __restrict__ out,
                                                             int K, int N) {
    __shared__ float t[32][33];
    int tx = threadIdx.x, ty = threadIdx.y;        // 32 x 8
    int n0 = blockIdx.x * 32, k0 = blockIdx.y * 32;
    #pragma unroll
    for (int i = ty; i < 32; i += 8)
        t[i][tx] = in[(size_t)(k0 + i) * N + n0 + tx];
    __syncthreads();
    #pragma unroll
    for (int i = ty; i < 32; i += 8)
        out[(size_t)(n0 + i) * K + k0 + tx] = __float2bfloat16(t[tx][i]);
}

// ---------------------------------------------------------------------------
// Fused FAVOR+ projection weights (cols 2304..3839 of W_ext) + bias_ext.
// ---------------------------------------------------------------------------
__global__ __launch_bounds__(256) void fuse_feat_kernel(const float* __restrict__ w_attn,
                                                        const float* __restrict__ b_attn,
                                                        const float* __restrict__ wfeat,
                                                        bf16* __restrict__ bt_ext,
                                                        float* __restrict__ bias_ext) {
    __shared__ float wfT[64][65];   // wfT[d][m] = scale*wf[m][d]
    __shared__ float Wt[64][65];    // Wt[j][d]
    int t = threadIdx.x;
    int j0 = blockIdx.x * 64, h = blockIdx.y, isK = blockIdx.z;
    int base = isK * DD + h * DHH;
    const float scale = 0.35355339059327373f;  // 64^-0.25
    #pragma unroll
    for (int it = 0; it < 16; it++) {
        int idx = it * 256 + t;
        int m = idx >> 6, d = idx & 63;
        wfT[d][m] = scale * wfeat[m * DHH + d];
        Wt[idx >> 6][idx & 63] = w_attn[(size_t)(j0 + (idx >> 6)) * (3 * DD) + base + (idx & 63)];
    }
    __syncthreads();
    int jl = t & 63, mg = (t >> 6) * 16;
    for (int m = mg; m < mg + 16; m++) {
        float acc = 0.f;
        #pragma unroll 8
        for (int d = 0; d < 64; d++) acc += wfT[d][m] * Wt[jl][d];
        bt_ext[(size_t)(PQOFF + isK * DD + h * DHH + m) * DD + j0 + jl] = __float2bfloat16(acc);
    }
    if (blockIdx.x == 0 && t < 64) {
        float accb = 0.f;
        #pragma unroll 8
        for (int d = 0; d < 64; d++) accb += wfT[d][t] * b_attn[base + d];
        bias_ext[PQOFF + isK * DD + h * DHH + t] = accb;
    }
}

// ---------------------------------------------------------------------------
// LayerNorm: one block per row, 256 threads; f32 in -> bf16 out.
// ---------------------------------------------------------------------------
__global__ __launch_bounds__(256) void ln_kernel(const float* __restrict__ x,
                                                 const float* __restrict__ g,
                                                 const float* __restrict__ bta,
                                                 bf16* __restrict__ out) {
    int row = blockIdx.x;
    int t = threadIdx.x;
    const float* xr = x + (size_t)row * DD;
    float v0 = xr[t], v1 = xr[t + 256], v2 = xr[t + 512];
    float s = v0 + v1 + v2;
    float s2 = v0 * v0 + v1 * v1 + v2 * v2;
    #pragma unroll
    for (int off = 32; off > 0; off >>= 1) {
        s  += __shfl_xor(s,  off, 64);
        s2 += __shfl_xor(s2, off, 64);
    }
    __shared__ float ls[4], ls2[4];
    if ((t & 63) == 0) { ls[t >> 6] = s; ls2[t >> 6] = s2; }
    __syncthreads();
    s  = ls[0] + ls[1] + ls[2] + ls[3];
    s2 = ls2[0] + ls2[1] + ls2[2] + ls2[3];
    float mu  = s * (1.0f / DD);
    float var = s2 * (1.0f / DD) - mu * mu;
    float r = rsqrtf(var + EPS_LN);
    bf16* orow = out + (size_t)row * DD;
    orow[t]       = __float2bfloat16((v0 - mu) * r * g[t]       + bta[t]);
    orow[t + 256] = __float2bfloat16((v1 - mu) * r * g[t + 256] + bta[t + 256]);
    orow[t + 512] = __float2bfloat16((v2 - mu) * r * g[t + 512] + bta[t + 512]);
}

// ---------------------------------------------------------------------------
// MFMA GEMM: C[2048 x N] = A[2048 x K](bf16) @ BT[N x K]^T + bias (+gelu)(+res)
// ---------------------------------------------------------------------------
__device__ inline float gelu_tanh(float x) {
    float x3 = x * x * x;
    float u = 0.7978845608028654f * (x + 0.044715f * x3);
    return 0.5f * x * (1.0f + tanhf(u));
}

template <int ACT, int HAS_RES, int OUT_BF16>
__global__ __launch_bounds__(256) void gemm_mfma_kernel(const bf16* __restrict__ A,
                                                        const bf16* __restrict__ BT,
                                                        const float* __restrict__ bias,
                                                        const float* __restrict__ res,
                                                        void* __restrict__ Cout,
                                                        int N, int K) {
    __shared__ bf16 Asl[64][40];
    __shared__ bf16 Bsl[64][40];
    int tid = threadIdx.x;
    int m0 = blockIdx.y * 64, n0 = blockIdx.x * 64;
    int wave = tid >> 6, lane = tid & 63;
    int qm = lane & 15, quad = lane >> 4;
    int sm = tid >> 2, sk = (tid & 3) * 8;

    v4f acc[4] = {{0.f,0.f,0.f,0.f},{0.f,0.f,0.f,0.f},{0.f,0.f,0.f,0.f},{0.f,0.f,0.f,0.f}};

    for (int k0 = 0; k0 < K; k0 += 32) {
        uint4 av = *(const uint4*)(A  + (size_t)(m0 + sm) * K + k0 + sk);
        uint4 bv = *(const uint4*)(BT + (size_t)(n0 + sm) * K + k0 + sk);
        __syncthreads();
        *(uint4*)&Asl[sm][sk] = av;
        *(uint4*)&Bsl[sm][sk] = bv;
        __syncthreads();
        v8s a = *(const v8s*)&Asl[wave * 16 + qm][quad * 8];
        #pragma unroll
        for (int t = 0; t < 4; t++) {
            v8s b = *(const v8s*)&Bsl[t * 16 + qm][quad * 8];
            acc[t] = __builtin_amdgcn_mfma_f32_16x16x32_bf16(a, b, acc[t], 0, 0, 0);
        }
    }

    int col_l = lane & 15;
    #pragma unroll
    for (int t = 0; t < 4; t++) {
        int col = n0 + t * 16 + col_l;
        float bcol = bias[col];
        #pragma unroll
        for (int r = 0; r < 4; r++) {
            int row = m0 + wave * 16 + quad * 4 + r;
            float v = acc[t][r] + bcol;
            if (ACT == 1) v = gelu_tanh(v);
            if (HAS_RES) v += res[(size_t)row * N + col];
            if (OUT_BF16) ((bf16*)Cout)[(size_t)row * N + col] = __float2bfloat16(v);
            else          ((float*)Cout)[(size_t)row * N + col] = v;
        }
    }
}

// ---------------------------------------------------------------------------
// phi in place over proj columns of qkvp.
// ---------------------------------------------------------------------------
__global__ __launch_bounds__(256) void phi_exp_kernel(float* __restrict__ qkvp) {
    int s = blockIdx.x, z = blockIdx.z;
    int b = z >> 1, isK = z & 1;
    int t = threadIdx.x;
    int h = blockIdx.y * 4 + (t >> 6);
    int m = t & 63;
    size_t row = (size_t)b * SS + s;
    float qd = qkvp[row * NQ + isK * DD + h * DHH + m];
    float sq = qd * qd;
    #pragma unroll
    for (int off = 32; off > 0; off >>= 1) sq += __shfl_xor(sq, off, 64);
    sq *= (1.0f / 16.0f);
    size_t pidx = row * NQ + PQOFF + isK * DD + h * DHH + m;
    float proj = qkvp[pidx];
    qkvp[pidx] = __expf(proj - sq) * 0.125f + EPS_PHI;
}

// ---------------------------------------------------------------------------
// Scan phase 1 (MFMA): per (b,h,c): StateT[d][m] = V^T @ phik ; Sk[m] = col-sum.
// 4 waves; wave w computes d-rows [16w,16w+16).
// ---------------------------------------------------------------------------
__global__ __launch_bounds__(256) void scan_sums_mfma(const float* __restrict__ qkvp,
                                                      float* __restrict__ StateT,
                                                      float* __restrict__ Sk) {
    int c = blockIdx.x, h = blockIdx.y, b = blockIdx.z;
    int bh = b * HH + h;
    int t = threadIdx.x;
    __shared__ bf16 vt[64][72];   // V^T[d][s]
    __shared__ bf16 kt[64][72];   // phik^T[m][s]
    int sr = t >> 4, cq = (t & 15) * 4;
    #pragma unroll
    for (int i = 0; i < 4; i++) {
        int s = sr + 16 * i;
        size_t rowg = ((size_t)b * SS + c * CC + s) * NQ + h * DHH;
        float4 vv = *(const float4*)&qkvp[rowg + VOFF  + cq];
        float4 kv = *(const float4*)&qkvp[rowg + PKOFF + cq];
        vt[cq + 0][s] = __float2bfloat16(vv.x);
        vt[cq + 1][s] = __float2bfloat16(vv.y);
        vt[cq + 2][s] = __float2bfloat16(vv.z);
        vt[cq + 3][s] = __float2bfloat16(vv.w);
        kt[cq + 0][s] = __float2bfloat16(kv.x);
        kt[cq + 1][s] = __float2bfloat16(kv.y);
        kt[cq + 2][s] = __float2bfloat16(kv.z);
        kt[cq + 3][s] = __float2bfloat16(kv.w);
    }
    __syncthreads();
    int wave = t >> 6, lane = t & 63, qm = lane & 15, quad = lane >> 4;
    v4f acc[4] = {{0.f,0.f,0.f,0.f},{0.f,0.f,0.f,0.f},{0.f,0.f,0.f,0.f},{0.f,0.f,0.f,0.f}};
    #pragma unroll
    for (int k0 = 0; k0 < 64; k0 += 32) {
        v8s a = *(const v8s*)&vt[wave * 16 + qm][k0 + quad * 8];
        #pragma unroll
        for (int n = 0; n < 4; n++) {
            v8s bb = *(const v8s*)&kt[n * 16 + qm][k0 + quad * 8];
            acc[n] = __builtin_amdgcn_mfma_f32_16x16x32_bf16(a, bb, acc[n], 0, 0, 0);
        }
    }
    float* dst = StateT + ((size_t)bh * NC + c) * 4096;
    int col_l = lane & 15;
    #pragma unroll
    for (int n = 0; n < 4; n++)
        #pragma unroll
        for (int r = 0; r < 4; r++) {
            int d = wave * 16 + quad * 4 + r;
            dst[d * 64 + n * 16 + col_l] = acc[n][r];
        }
    if (t < 64) {
        float sum = 0.f;
        #pragma unroll 8
        for (int i = 0; i < 64; i++) sum += __bfloat162float(kt[t][i]);
        Sk[((size_t)bh * NC + c) * 64 + t] = sum;
    }
}

// ---------------------------------------------------------------------------
// Scan phase 2: in-place EXCLUSIVE prefix over chunks (unchanged).
// ---------------------------------------------------------------------------
__global__ __launch_bounds__(256) void scan_prefix_kernel(float* __restrict__ Skv,
                                                          float* __restrict__ Sk) {
    int bh = blockIdx.y;
    int t = blockIdx.x * 256 + threadIdx.x;
    size_t base = (size_t)bh * NC * 4096 + t;
    float acc = 0.f;
    for (int c = 0; c < NC; c++) {
        float v = Skv[base + (size_t)c * 4096];
        Skv[base + (size_t)c * 4096] = acc;
        acc += v;
    }
    if (blockIdx.x == 0 && threadIdx.x < 64) {
        size_t b2 = (size_t)bh * NC * 64 + threadIdx.x;
        float a2 = 0.f;
        for (int c = 0; c < NC; c++) {
            float v = Sk[b2 + (size_t)c * 64];
            Sk[b2 + (size_t)c * 64] = a2;
            a2 += v;
        }
    }
}

// ---------------------------------------------------------------------------
// Scan phase 3 (MFMA): per (b,h,c):
//   A1 = phiq @ phik^T  (mask tril incl. diag -> P, bf16, LDS)
//   acc = phiq @ [StateT | SkPre]^T + P @ [V | 1]   (5 n-tiles; tile4 col0 = den)
//   attn = num / den
// den trick: vt row 64 = ones, stl row 64 = SkPre; rows 65..79 zero.
// ---------------------------------------------------------------------------
__global__ __launch_bounds__(256) void scan_chunk_mfma(const float* __restrict__ qkvp,
                                                       const float* __restrict__ StateT,
                                                       const float* __restrict__ SkPre,
                                                       bf16* __restrict__ attn) {
    int c = blockIdx.x, h = blockIdx.y, b = blockIdx.z;
    int bh = b * HH + h;
    int t = threadIdx.x;
    __shared__ bf16 qs[64][72];    // phiq[s][m]
    __shared__ bf16 ks[64][72];    // phik[s'][m]
    __shared__ bf16 vt[80][72];    // V^T[d][s'] (+ones row 64)
    __shared__ bf16 stl[80][72];   // StateT[d][m] (+SkPre row 64)
    __shared__ bf16 P[64][72];     // masked A1 [s][s']
    int sr = t >> 4, cq = (t & 15) * 4;
    const float* stg = StateT + ((size_t)bh * NC + c) * 4096;
    #pragma unroll
    for (int i = 0; i < 4; i++) {
        int s = sr + 16 * i;
        size_t rowg = ((size_t)b * SS + c * CC + s) * NQ + h * DHH;
        float4 qv = *(const float4*)&qkvp[rowg + PQOFF + cq];
        float4 kv = *(const float4*)&qkvp[rowg + PKOFF + cq];
        float4 vv = *(const float4*)&qkvp[rowg + VOFF  + cq];
        float4 sv = *(const float4*)&stg[s * 64 + cq];
        qs[s][cq + 0] = __float2bfloat16(qv.x);
        qs[s][cq + 1] = __float2bfloat16(qv.y);
        qs[s][cq + 2] = __float2bfloat16(qv.z);
        qs[s][cq + 3] = __float2bfloat16(qv.w);
        ks[s][cq + 0] = __float2bfloat16(kv.x);
        ks[s][cq + 1] = __float2bfloat16(kv.y);
        ks[s][cq + 2] = __float2bfloat16(kv.z);
        ks[s][cq + 3] = __float2bfloat16(kv.w);
        vt[cq + 0][s] = __float2bfloat16(vv.x);
        vt[cq + 1][s] = __float2bfloat16(vv.y);
        vt[cq + 2][s] = __float2bfloat16(vv.z);
        vt[cq + 3][s] = __float2bfloat16(vv.w);
        stl[s][cq + 0] = __float2bfloat16(sv.x);
        stl[s][cq + 1] = __float2bfloat16(sv.y);
        stl[s][cq + 2] = __float2bfloat16(sv.z);
        stl[s][cq + 3] = __float2bfloat16(sv.w);
    }
    {   // extra rows 64..79
        int rr = 64 + (t >> 4);
        bf16 one = __float2bfloat16(rr == 64 ? 1.f : 0.f);
        vt[rr][cq + 0] = one; vt[rr][cq + 1] = one;
        vt[rr][cq + 2] = one; vt[rr][cq + 3] = one;
        if (rr == 64) {
            const float* skp = SkPre + ((size_t)bh * NC + c) * 64;
            float4 s4 = *(const float4*)&skp[cq];
            stl[64][cq + 0] = __float2bfloat16(s4.x);
            stl[64][cq + 1] = __float2bfloat16(s4.y);
            stl[64][cq + 2] = __float2bfloat16(s4.z);
            stl[64][cq + 3] = __float2bfloat16(s4.w);
        } else {
            bf16 z = __float2bfloat16(0.f);
            stl[rr][cq + 0] = z; stl[rr][cq + 1] = z;
            stl[rr][cq + 2] = z; stl[rr][cq + 3] = z;
        }
    }
    __syncthreads();
    int wave = t >> 6, lane = t & 63, qm = lane & 15, quad = lane >> 4;
    int col_l = lane & 15;
    int row0 = wave * 16;

    // A1 = phiq @ phik^T
    v4f a1[4] = {{0.f,0.f,0.f,0.f},{0.f,0.f,0.f,0.f},{0.f,0.f,0.f,0.f},{0.f,0.f,0.f,0.f}};
    #pragma unroll
    for (int k0 = 0; k0 < 64; k0 += 32) {
        v8s a = *(const v8s*)&qs[row0 + qm][k0 + quad * 8];
        #pragma unroll
        for (int n = 0; n < 4; n++) {
            v8s bb = *(const v8s*)&ks[n * 16 + qm][k0 + quad * 8];
            a1[n] = __builtin_amdgcn_mfma_f32_16x16x32_bf16(a, bb, a1[n], 0, 0, 0);
        }
    }
    // mask -> P (each wave writes & later reads only its own 16 rows)
    #pragma unroll
    for (int n = 0; n < 4; n++)
        #pragma unroll
        for (int r = 0; r < 4; r++) {
            int row = row0 + quad * 4 + r;
            int col = n * 16 + col_l;
            float v = (col <= row) ? a1[n][r] : 0.f;
            P[row][col] = __float2bfloat16(v);
        }
    // num/den
    v4f acc[5] = {{0.f,0.f,0.f,0.f},{0.f,0.f,0.f,0.f},{0.f,0.f,0.f,0.f},
                  {0.f,0.f,0.f,0.f},{0.f,0.f,0.f,0.f}};
    #pragma unroll
    for (int k0 = 0; k0 < 64; k0 += 32) {
        v8s aq = *(const v8s*)&qs[row0 + qm][k0 + quad * 8];
        v8s ap = *(const v8s*)&P [row0 + qm][k0 + quad * 8];
        #pragma unroll
        for (int n = 0; n < 5; n++) {
            v8s b1 = *(const v8s*)&stl[n * 16 + qm][k0 + quad * 8];
            v8s b2 = *(const v8s*)&vt [n * 16 + qm][k0 + quad * 8];
            acc[n] = __builtin_amdgcn_mfma_f32_16x16x32_bf16(aq, b1, acc[n], 0, 0, 0);
            acc[n] = __builtin_amdgcn_mfma_f32_16x16x32_bf16(ap, b2, acc[n], 0, 0, 0);
        }
    }
    // den = tile4 col0; broadcast from lane quad*16 within each quad
    float den[4];
    #pragma unroll
    for (int r = 0; r < 4; r++)
        den[r] = __shfl(acc[4][r], (lane >> 4) << 4, 64);
    // write attn
    #pragma unroll
    for (int n = 0; n < 4; n++)
        #pragma unroll
        for (int r = 0; r < 4; r++) {
            int srow = row0 + quad * 4 + r;
            int d = n * 16 + col_l;
            attn[((size_t)b * SS + c * CC + srow) * DD + h * DHH + d] =
                __float2bfloat16(acc[n][r] / den[r]);
        }
}

// ---------------------------------------------------------------------------
extern "C" void kernel_launch(void* const* d_in, const int* in_sizes, int n_in,
                              void* d_out, int out_size, void* d_ws, size_t ws_size,
                              hipStream_t stream) {
    const float* x      = (const float*)d_in[0];
    const float* ln1_g  = (const float*)d_in[1];
    const float* ln1_b  = (const float*)d_in[2];
    const float* w_attn = (const float*)d_in[3];
    const float* b_attn = (const float*)d_in[4];
    const float* w_feat = (const float*)d_in[5];
    const float* w_proj = (const float*)d_in[6];
    const float* b_proj = (const float*)d_in[7];
    const float* ln2_g  = (const float*)d_in[8];
    const float* ln2_b  = (const float*)d_in[9];
    const float* w_fc   = (const float*)d_in[10];
    const float* b_fc   = (const float*)d_in[11];
    const float* w_out  = (const float*)d_in[12];
    const float* b_out  = (const float*)d_in[13];
    float* out = (float*)d_out;

    // f32 region
    float* ws = (float*)d_ws;
    size_t off = 0;
    float* buf_qkvp = ws + off; off += (size_t)BS * NQ;            // 7.86M f32
    float* buf_x1   = ws + off; off += (size_t)BS * DD;            // 1.57M
    float* buf_sk   = ws + off; off += (size_t)BB * HH * NC * MM;  // 24.6K
    float* bias_ext = ws + off; off += NQ;
    // bf16 region
    bf16* wb = (bf16*)(ws + off);
    size_t boff = 0;
    bf16* buf_a_bf    = wb + boff; boff += (size_t)BS * DD;
    bf16* buf_attn_bf = wb + boff; boff += (size_t)BS * DD;
    bf16* wext_t      = wb + boff; boff += (size_t)NQ * DD;
    bf16* wproj_t     = wb + boff; boff += (size_t)DD * DD;
    bf16* wfc_t       = wb + boff; boff += (size_t)DFF * DD;
    bf16* wout_t      = wb + boff; boff += (size_t)DD * DFF;
    // Aliases: StateT (1.57M f32) over buf_x1; fc bf16 over dead qkvp head.
    float* buf_skv   = buf_x1;
    bf16*  buf_fc_bf = (bf16*)buf_qkvp;

    // 0) weight prep
    transpose_cast_kernel<<<dim3(3 * DD / 32, DD / 32), dim3(32, 8), 0, stream>>>(w_attn, wext_t, DD, 3 * DD);
    fuse_feat_kernel<<<dim3(DD / 64, HH, 2), 256, 0, stream>>>(w_attn, b_attn, w_feat, wext_t, bias_ext);
    hipMemcpyAsync(bias_ext, b_attn, 3 * DD * sizeof(float), hipMemcpyDeviceToDevice, stream);
    transpose_cast_kernel<<<dim3(DD / 32, DD / 32),  dim3(32, 8), 0, stream>>>(w_proj, wproj_t, DD, DD);
    transpose_cast_kernel<<<dim3(DFF / 32, DD / 32), dim3(32, 8), 0, stream>>>(w_fc,   wfc_t,   DD, DFF);
    transpose_cast_kernel<<<dim3(DD / 32, DFF / 32), dim3(32, 8), 0, stream>>>(w_out,  wout_t,  DFF, DD);

    // 1) a = LN1(x) -> bf16
    ln_kernel<<<BS, 256, 0, stream>>>(x, ln1_g, ln1_b, buf_a_bf);
    // 2) [qkv | proj_q | proj_k] = a @ W_ext + bias_ext
    gemm_mfma_kernel<0, 0, 0><<<dim3(NQ / 64, BS / 64), 256, 0, stream>>>(
        buf_a_bf, wext_t, bias_ext, nullptr, buf_qkvp, NQ, DD);
    // 3) phi in place
    phi_exp_kernel<<<dim3(SS, 3, 2 * BB), 256, 0, stream>>>(buf_qkvp);
    // 4a) per-chunk sums (MFMA)
    scan_sums_mfma<<<dim3(NC, HH, BB), 256, 0, stream>>>(buf_qkvp, buf_skv, buf_sk);
    // 4b) exclusive prefix over chunks
    scan_prefix_kernel<<<dim3(4096 / 256, BB * HH), 256, 0, stream>>>(buf_skv, buf_sk);
    // 4c) per-chunk masked-MFMA scan -> attn (bf16)
    scan_chunk_mfma<<<dim3(NC, HH, BB), 256, 0, stream>>>(
        buf_qkvp, buf_skv, buf_sk, buf_attn_bf);
    // 5) x1 = x + attn @ w_proj + b_proj
    gemm_mfma_kernel<0, 1, 0><<<dim3(DD / 64, BS / 64), 256, 0, stream>>>(
        buf_attn_bf, wproj_t, b_proj, x, buf_x1, DD, DD);
    // 6) m = LN2(x1) -> bf16
    ln_kernel<<<BS, 256, 0, stream>>>(buf_x1, ln2_g, ln2_b, buf_a_bf);
    // 7) fc = gelu(m @ w_fc + b_fc) -> bf16
    gemm_mfma_kernel<1, 0, 1><<<dim3(DFF / 64, BS / 64), 256, 0, stream>>>(
        buf_a_bf, wfc_t, b_fc, nullptr, buf_fc_bf, DFF, DD);
    // 8) out = x1 + fc @ w_out + b_out
    gemm_mfma_kernel<0, 1, 0><<<dim3(DD / 64, BS / 64), 256, 0, stream>>>(
        buf_fc_bf, wout_t, b_out, buf_x1, out, DD, DFF);
}